// Round 6
// baseline (471.155 us; speedup 1.0000x reference)
//
#include <hip/hip_runtime.h>

// ---------------------------------------------------------------------------
// LinearAttention forward. Inputs/outputs FLOAT32; internal compute bf16 MFMA
// with fp32 accumulation. B=2, T=8192 (BT=16384), HID=1024, H=8, DK=DV=128.
// ws layout (MB): [0,32) Q (O in-place) | [32,64) Kf | [64,96) VT |
//   [96,160) KV (Xb bf16 overlays [96,128) until QKV GEMM done) |
//   [160,168) Wq/Wk/Wv/Wo bf16 | [168,+128KB) fm weights bf16
// NOTE (R4 post-mortem): do NOT fuse the feature map into qkv_gemm's epilogue —
// +34.8KB LDS / +128 VGPR -> ~1 block/CU -> 140->291 us.
// R6: big GEMMs use v_mfma_f32_32x32x16_bf16 (m119: 2495 vs 2176 TF pipe rate,
// same LDS traffic). C/D: col=lane&31, row=(reg&3)+8*(reg>>2)+4*(lane>>5).
// ---------------------------------------------------------------------------

typedef __bf16 bf16x8 __attribute__((ext_vector_type(8)));
typedef float  f32x4  __attribute__((ext_vector_type(4)));
typedef float  f32x16 __attribute__((ext_vector_type(16)));

__device__ __forceinline__ float bf2f(unsigned short u) {
  union { unsigned int i; float f; } v; v.i = ((unsigned int)u) << 16; return v.f;
}
__device__ __forceinline__ unsigned short f2bf(float f) {
  union { float f; unsigned int i; } v; v.f = f;
  return (unsigned short)((v.i + 0x8000u) >> 16);  // round-half-up
}
__device__ __forceinline__ unsigned int pk2(float a, float b) {
  union { float f; unsigned int i; } x, y; x.f = a; y.f = b;
  return ((x.i + 0x8000u) >> 16) | ((y.i + 0x8000u) & 0xFFFF0000u);
}
__device__ __forceinline__ f32x4 mfma16(bf16x8 a, bf16x8 b, f32x4 c) {
  return __builtin_amdgcn_mfma_f32_16x16x32_bf16(a, b, c, 0, 0, 0);
}
__device__ __forceinline__ f32x16 mfma32(bf16x8 a, bf16x8 b, f32x16 c) {
  return __builtin_amdgcn_mfma_f32_32x32x16_bf16(a, b, c, 0, 0, 0);
}
// Async global->LDS, 16B per lane. LDS dest = wave-uniform base + lane*16.
__device__ __forceinline__ void gl_lds16(const unsigned short* g, unsigned short* l) {
  __builtin_amdgcn_global_load_lds((const __attribute__((address_space(1))) void*)g,
                                   (__attribute__((address_space(3))) void*)l, 16, 0, 0);
}

// ---------------------------------------------------------------------------
// f32 -> bf16 converters. cvt4: four tensors in one launch (blockIdx.y picks).
// ---------------------------------------------------------------------------
__global__ void __launch_bounds__(256)
cvt_kernel(const float* __restrict__ s, unsigned short* __restrict__ d, int n4) {
  const int i = blockIdx.x * 256 + threadIdx.x;
  if (i >= n4) return;
  const float4 f = ((const float4*)s)[i];
  uint2 o; o.x = pk2(f.x, f.y); o.y = pk2(f.z, f.w);
  ((uint2*)d)[i] = o;
}
__global__ void __launch_bounds__(256)
cvt4_kernel(const float* __restrict__ s0, const float* __restrict__ s1,
            const float* __restrict__ s2, const float* __restrict__ s3,
            unsigned short* __restrict__ d0, unsigned short* __restrict__ d1,
            unsigned short* __restrict__ d2, unsigned short* __restrict__ d3,
            int n4) {
  const int w = blockIdx.y;
  const float* s = (w == 0) ? s0 : (w == 1) ? s1 : (w == 2) ? s2 : s3;
  unsigned short* d = (w == 0) ? d0 : (w == 1) ? d1 : (w == 2) ? d2 : d3;
  const int i = blockIdx.x * 256 + threadIdx.x;
  if (i >= n4) return;
  const float4 f = ((const float4*)s)[i];
  uint2 o; o.x = pk2(f.x, f.y); o.y = pk2(f.z, f.w);
  ((uint2*)d)[i] = o;
}

// ---------------------------------------------------------------------------
// Fused QKV GEMM (m97 staging, 32x32x16 MFMA): C[16384,3072] = Xb*[Wq;Wk;Wv]^T.
// Grid (24, 128): sel = bx>>3 (0=Q,1=K,2=V), (bx&7)*128 = col base.
// 128x128 tile, BK=32, 256 threads; each wave 64x64 = 2x2 tiles of 32x32.
// ---------------------------------------------------------------------------
__global__ void __launch_bounds__(256)
qkv_gemm(const unsigned short* __restrict__ Xb,
         const unsigned short* __restrict__ Wqb, const unsigned short* __restrict__ Wkb,
         const unsigned short* __restrict__ Wvb,
         unsigned short* __restrict__ Q, unsigned short* __restrict__ Kf,
         unsigned short* __restrict__ VT) {
  constexpr int K = 1024;
  __shared__ unsigned short As[128 * 32];
  __shared__ unsigned short Bs[128 * 32];
  const int tid = threadIdx.x;
  const int bx = blockIdx.x;
  const int rowBase = blockIdx.y * 128;
  const int sel = bx >> 3;
  const int colBase = (bx & 7) * 128;
  const unsigned short* Bw = (sel == 0) ? Wqb : ((sel == 1) ? Wkb : Wvb);

  const int lane = tid & 63, wid = tid >> 6;
  const int l31 = lane & 31, half = lane >> 5;
  const int wm = (wid >> 1) * 64, wn = (wid & 1) * 64;

  const int srow = wid * 32 + (lane >> 2);
  const int scol = (lane & 3) * 8;
  const unsigned short* gA = Xb + (size_t)(rowBase + srow) * K + scol;
  const unsigned short* gB = Bw + (size_t)(colBase + srow) * K + scol;
  unsigned short* lA0 = As + wid * 1024;
  unsigned short* lA1 = As + wid * 1024 + 512;
  unsigned short* lB0 = Bs + wid * 1024;
  unsigned short* lB1 = Bs + wid * 1024 + 512;

  f32x16 acc[2][2] = {};
  for (int kt = 0; kt < K / 32; ++kt) {
    __syncthreads();
    gl_lds16(gA + kt * 32, lA0);
    gl_lds16(gA + kt * 32 + 16 * K, lA1);
    gl_lds16(gB + kt * 32, lB0);
    gl_lds16(gB + kt * 32 + 16 * K, lB1);
    __syncthreads();
#pragma unroll
    for (int ks = 0; ks < 2; ++ks) {
      const int ko = ks * 16 + half * 8;
      bf16x8 a0 = *(const bf16x8*)(As + (wm + l31) * 32 + ko);
      bf16x8 a1 = *(const bf16x8*)(As + (wm + 32 + l31) * 32 + ko);
      bf16x8 b0 = *(const bf16x8*)(Bs + (wn + l31) * 32 + ko);
      bf16x8 b1 = *(const bf16x8*)(Bs + (wn + 32 + l31) * 32 + ko);
      acc[0][0] = mfma32(a0, b0, acc[0][0]);
      acc[0][1] = mfma32(a0, b1, acc[0][1]);
      acc[1][0] = mfma32(a1, b0, acc[1][0]);
      acc[1][1] = mfma32(a1, b1, acc[1][1]);
    }
  }
  // C/D layout (32x32): col = lane&31, row = (r&3) + 8*(r>>2) + 4*half
  if (sel < 2) {
    unsigned short* C = (sel == 0) ? Q : Kf;
#pragma unroll
    for (int i = 0; i < 2; ++i)
#pragma unroll
      for (int j = 0; j < 2; ++j) {
        const int col = colBase + wn + j * 32 + l31;
#pragma unroll
        for (int a = 0; a < 4; ++a) {
          const int row0 = rowBase + wm + i * 32 + a * 8 + half * 4;
#pragma unroll
          for (int b4 = 0; b4 < 4; ++b4)
            C[(size_t)(row0 + b4) * 1024 + col] = f2bf(acc[i][j][a * 4 + b4]);
        }
      }
  } else {
#pragma unroll
    for (int i = 0; i < 2; ++i)
#pragma unroll
      for (int j = 0; j < 2; ++j) {
        const int col = colBase + wn + j * 32 + l31;   // 0..1023
        const int h = col >> 7, dv = col & 127;
#pragma unroll
        for (int a = 0; a < 4; ++a) {
          const int row0 = rowBase + wm + i * 32 + a * 8 + half * 4;  // 4 consec tokens
          const int b = row0 >> 13, tl = row0 & 8191;
          ushort4 t4;
          t4.x = f2bf(acc[i][j][a * 4 + 0]); t4.y = f2bf(acc[i][j][a * 4 + 1]);
          t4.z = f2bf(acc[i][j][a * 4 + 2]); t4.w = f2bf(acc[i][j][a * 4 + 3]);
          *(ushort4*)(VT + (((size_t)(b * 8 + h) * 128 + dv) << 13) + tl) = t4;
        }
      }
  }
}

// ---------------------------------------------------------------------------
// Final GEMM (m97 staging, 32x32x16 MFMA): out[16384,1024] f32 = O * Wo^T.
// ---------------------------------------------------------------------------
__global__ void __launch_bounds__(256)
out_gemm(const unsigned short* __restrict__ A, const unsigned short* __restrict__ Bw,
         float* __restrict__ C) {
  constexpr int K = 1024;
  __shared__ unsigned short As[128 * 32];
  __shared__ unsigned short Bs[128 * 32];
  const int tid = threadIdx.x;
  const int rowBase = blockIdx.y * 128;
  const int colBase = blockIdx.x * 128;
  const int lane = tid & 63, wid = tid >> 6;
  const int l31 = lane & 31, half = lane >> 5;
  const int wm = (wid >> 1) * 64, wn = (wid & 1) * 64;

  const int srow = wid * 32 + (lane >> 2);
  const int scol = (lane & 3) * 8;
  const unsigned short* gA = A + (size_t)(rowBase + srow) * K + scol;
  const unsigned short* gB = Bw + (size_t)(colBase + srow) * K + scol;
  unsigned short* lA0 = As + wid * 1024;
  unsigned short* lA1 = As + wid * 1024 + 512;
  unsigned short* lB0 = Bs + wid * 1024;
  unsigned short* lB1 = Bs + wid * 1024 + 512;

  f32x16 acc[2][2] = {};
  for (int kt = 0; kt < K / 32; ++kt) {
    __syncthreads();
    gl_lds16(gA + kt * 32, lA0);
    gl_lds16(gA + kt * 32 + 16 * K, lA1);
    gl_lds16(gB + kt * 32, lB0);
    gl_lds16(gB + kt * 32 + 16 * K, lB1);
    __syncthreads();
#pragma unroll
    for (int ks = 0; ks < 2; ++ks) {
      const int ko = ks * 16 + half * 8;
      bf16x8 a0 = *(const bf16x8*)(As + (wm + l31) * 32 + ko);
      bf16x8 a1 = *(const bf16x8*)(As + (wm + 32 + l31) * 32 + ko);
      bf16x8 b0 = *(const bf16x8*)(Bs + (wn + l31) * 32 + ko);
      bf16x8 b1 = *(const bf16x8*)(Bs + (wn + 32 + l31) * 32 + ko);
      acc[0][0] = mfma32(a0, b0, acc[0][0]);
      acc[0][1] = mfma32(a0, b1, acc[0][1]);
      acc[1][0] = mfma32(a1, b0, acc[1][0]);
      acc[1][1] = mfma32(a1, b1, acc[1][1]);
    }
  }
#pragma unroll
  for (int i = 0; i < 2; ++i)
#pragma unroll
    for (int j = 0; j < 2; ++j) {
      const int col = colBase + wn + j * 32 + l31;
#pragma unroll
      for (int a = 0; a < 4; ++a) {
        const int row0 = rowBase + wm + i * 32 + a * 8 + half * 4;
#pragma unroll
        for (int b4 = 0; b4 < 4; ++b4)
          C[(size_t)(row0 + b4) * 1024 + col] = acc[i][j][a * 4 + b4];
      }
    }
}

// ---------------------------------------------------------------------------
// Feature map (per head): buf = (buf@w1^T + b1) * (buf@w2^T + b2) * scale,
// in place. Grid (BT/64, 8, 2): z=0 -> Q params, z=1 -> K params.
// ---------------------------------------------------------------------------
__global__ void __launch_bounds__(256)
fm_kernel(unsigned short* __restrict__ Qb, unsigned short* __restrict__ Kb,
          const unsigned short* __restrict__ fq1b, const unsigned short* __restrict__ fq2b,
          const unsigned short* __restrict__ fk1b, const unsigned short* __restrict__ fk2b,
          const float* __restrict__ fqb1, const float* __restrict__ fqb2,
          const float* __restrict__ fkb1, const float* __restrict__ fkb2) {
  __shared__ unsigned short Aq[64 * 136];
  const int z = blockIdx.z;
  unsigned short* buf = z ? Kb : Qb;
  const unsigned short* w1b = z ? fk1b : fq1b;
  const unsigned short* w2b = z ? fk2b : fq2b;
  const float* b1 = z ? fkb1 : fqb1;
  const float* b2 = z ? fkb2 : fqb2;
  const float scale = z ? 1.0f : 0.08838834764831843f;

  const int tid = threadIdx.x;
  const int t0 = blockIdx.x * 64;
  const int h = blockIdx.y, hc = h * 128;
#pragma unroll
  for (int it = 0; it < 4; ++it) {
    const int p = tid + it * 256;
    const int row = p >> 4, c8 = (p & 15) * 8;
    *(uint4*)(Aq + row * 136 + c8) =
        *(const uint4*)(buf + (size_t)(t0 + row) * 1024 + hc + c8);
  }
  __syncthreads();
  const int lane = tid & 63, wid = tid >> 6, lq = lane & 15, quad = lane >> 4;
  const int wn = wid * 32;
  f32x4 a1[4][2] = {}, a2[4][2] = {};
#pragma unroll
  for (int ks = 0; ks < 4; ++ks) {
    bf16x8 af[4];
#pragma unroll
    for (int i = 0; i < 4; ++i)
      af[i] = *(const bf16x8*)(Aq + (i * 16 + lq) * 136 + ks * 32 + quad * 8);
#pragma unroll
    for (int j = 0; j < 2; ++j) {
      const int nr = wn + j * 16 + lq;
      bf16x8 w1f = *(const bf16x8*)(w1b + nr * 128 + ks * 32 + quad * 8);
      bf16x8 w2f = *(const bf16x8*)(w2b + nr * 128 + ks * 32 + quad * 8);
#pragma unroll
      for (int i = 0; i < 4; ++i) {
        a1[i][j] = mfma16(af[i], w1f, a1[i][j]);
        a2[i][j] = mfma16(af[i], w2f, a2[i][j]);
      }
    }
  }
#pragma unroll
  for (int j = 0; j < 2; ++j) {
    const int col = wn + j * 16 + lq;
    const float bb1 = b1[col], bb2 = b2[col];
#pragma unroll
    for (int i = 0; i < 4; ++i)
#pragma unroll
      for (int r = 0; r < 4; ++r) {
        const float v = (a1[i][j][r] + bb1) * (a2[i][j][r] + bb2) * scale;
        buf[(size_t)(t0 + i * 16 + quad * 4 + r) * 1024 + hc + col] = f2bf(v);
      }
  }
}

// ---------------------------------------------------------------------------
// Per-chunk KV outer product: KV[bh,n][dv][dk] = sum_c V[c][dv] * K[c][dk].
// ---------------------------------------------------------------------------
__global__ void __launch_bounds__(256)
kv_kernel(const unsigned short* __restrict__ Kf, const unsigned short* __restrict__ VT,
          unsigned short* __restrict__ KV) {
  __shared__ unsigned short Kt[128 * 72];
  __shared__ unsigned short Vt[128 * 72];
  const int tid = threadIdx.x;
  const int n = blockIdx.x, bh = blockIdx.y;
  const int b = bh >> 3, h = bh & 7;
  const int t0g = b * 8192 + n * 64;
  const int tl0 = n * 64;
#pragma unroll
  for (int it = 0; it < 4; ++it) {
    const int p = tid + it * 256;
    const int d = p >> 3, c8 = (p & 7) * 8;
    *(uint4*)(Vt + d * 72 + c8) =
        *(const uint4*)(VT + (((size_t)bh * 128 + d) << 13) + tl0 + c8);
    const int tok = p >> 4, c8k = (p & 15) * 8;
    const unsigned short* src = Kf + (size_t)(t0g + tok) * 1024 + h * 128 + c8k;
    ushort4 k0 = *(const ushort4*)(src);
    ushort4 k1 = *(const ushort4*)(src + 4);
    Kt[(c8k + 0) * 72 + tok] = k0.x; Kt[(c8k + 1) * 72 + tok] = k0.y;
    Kt[(c8k + 2) * 72 + tok] = k0.z; Kt[(c8k + 3) * 72 + tok] = k0.w;
    Kt[(c8k + 4) * 72 + tok] = k1.x; Kt[(c8k + 5) * 72 + tok] = k1.y;
    Kt[(c8k + 6) * 72 + tok] = k1.z; Kt[(c8k + 7) * 72 + tok] = k1.w;
  }
  __syncthreads();
  const int lane = tid & 63, wid = tid >> 6, lq = lane & 15, quad = lane >> 4;
  const int wm = (wid >> 1) * 64, wn = (wid & 1) * 64;
  f32x4 acc[4][4] = {};
#pragma unroll
  for (int ks = 0; ks < 2; ++ks) {
    bf16x8 af[4], bfr[4];
#pragma unroll
    for (int i = 0; i < 4; ++i)
      af[i] = *(const bf16x8*)(Vt + (wm + i * 16 + lq) * 72 + ks * 32 + quad * 8);
#pragma unroll
    for (int j = 0; j < 4; ++j)
      bfr[j] = *(const bf16x8*)(Kt + (wn + j * 16 + lq) * 72 + ks * 32 + quad * 8);
#pragma unroll
    for (int i = 0; i < 4; ++i)
#pragma unroll
      for (int j = 0; j < 4; ++j) acc[i][j] = mfma16(af[i], bfr[j], acc[i][j]);
  }
  const size_t base = ((size_t)bh * 128 + n) * 16384;
#pragma unroll
  for (int i = 0; i < 4; ++i)
#pragma unroll
    for (int j = 0; j < 4; ++j)
#pragma unroll
      for (int r = 0; r < 4; ++r)
        KV[base + (size_t)(wm + i * 16 + quad * 4 + r) * 128 + wn + j * 16 + lq] =
            f2bf(acc[i][j][r]);
}

// ---------------------------------------------------------------------------
// Exclusive prefix sum of per-chunk KV states over n (128 chunks), in place.
// ---------------------------------------------------------------------------
__global__ void __launch_bounds__(256)
cumsum_kernel(unsigned short* __restrict__ KV) {
  const int idx = blockIdx.x * 256 + threadIdx.x;  // 0..262143
  const int bh = idx >> 14, e = idx & 16383;
  unsigned short* p = KV + (size_t)bh * (128 * 16384) + e;
  float run = 0.f;
  for (int n = 0; n < 128; ++n) {
    const float x = bf2f(*p);
    *p = f2bf(run);  // exclusive
    run += x;
    p += 16384;
  }
}

// ---------------------------------------------------------------------------
// Attention chunk kernel: o = tril(q k^T) v + q S, fused RMSNorm, per (b,h,n).
// O aliases Q (global Q reads only in phase 1; O written in phase 9).
// ---------------------------------------------------------------------------
__global__ void __launch_bounds__(256)
attn_kernel(const unsigned short* __restrict__ Q, const unsigned short* __restrict__ Kf,
            const unsigned short* __restrict__ VT, const unsigned short* __restrict__ S,
            const float* __restrict__ rmsw, unsigned short* __restrict__ O) {
  __shared__ uint4 smem4[3968];  // 63488 B
  unsigned short* sm = (unsigned short*)smem4;
  unsigned short* SQ = sm;            // stride 136
  unsigned short* KS = sm + 8704;
  unsigned short* VTl = sm + 17920;   // stride 72
  unsigned short* AL = sm + 27136;    // stride 72
  float* OL = (float*)sm;             // stride 132
  float* RED = (float*)AL;
  float* SCL = RED + 256;

  const int tid = threadIdx.x;
  const int n = blockIdx.x, bh = blockIdx.y;
  const int b = bh >> 3, h = bh & 7;
  const int t0g = b * 8192 + n * 64;
  const int tl0 = n * 64;
  const int lane = tid & 63, wid = tid >> 6, lq = lane & 15, quad = lane >> 4;

  // Phase 1: stage q, k (row-major) and V^T.
#pragma unroll
  for (int it = 0; it < 4; ++it) {
    const int p = tid + it * 256;
    const int row = p >> 4, c8 = (p & 15) * 8;
    *(uint4*)(SQ + row * 136 + c8) =
        *(const uint4*)(Q + (size_t)(t0g + row) * 1024 + h * 128 + c8);
    *(uint4*)(KS + row * 136 + c8) =
        *(const uint4*)(Kf + (size_t)(t0g + row) * 1024 + h * 128 + c8);
    const int d = p >> 3, c8b = (p & 7) * 8;
    *(uint4*)(VTl + d * 72 + c8b) =
        *(const uint4*)(VT + (((size_t)bh * 128 + d) << 13) + tl0 + c8b);
  }
  __syncthreads();

  // Phase 2: A = q k^T (wave w owns k-positions w*16..+15), mask, -> AL.
  {
    f32x4 aa[4] = {};
#pragma unroll
    for (int ks = 0; ks < 4; ++ks) {
      bf16x8 kf = *(const bf16x8*)(KS + (wid * 16 + lq) * 136 + ks * 32 + quad * 8);
#pragma unroll
      for (int i = 0; i < 4; ++i) {
        bf16x8 qf = *(const bf16x8*)(SQ + (i * 16 + lq) * 136 + ks * 32 + quad * 8);
        aa[i] = mfma16(qf, kf, aa[i]);
      }
    }
#pragma unroll
    for (int i = 0; i < 4; ++i)
#pragma unroll
      for (int r = 0; r < 4; ++r) {
        const int qp = i * 16 + quad * 4 + r, kp = wid * 16 + lq;
        AL[qp * 72 + kp] = f2bf(kp <= qp ? aa[i][r] : 0.f);
      }
  }
  __syncthreads();

  const size_t sbase = ((size_t)bh * 128 + n) * 16384;
  // Phase 3: stage S^T half 1 (dk 0..63) over KS.
#pragma unroll
  for (int it = 0; it < 4; ++it) {
    const int p = tid + it * 256;
    const int dv = p >> 3, c8 = (p & 7) * 8;
    *(uint4*)(KS + dv * 72 + c8) = *(const uint4*)(S + sbase + (size_t)dv * 128 + c8);
  }
  __syncthreads();

  f32x4 oa[4][2] = {};
  // Phase 4: o += A_masked * V  and  o += q[:,0:64] * S[0:64,:].
#pragma unroll
  for (int ks = 0; ks < 2; ++ks) {
    bf16x8 bv[2], sf[2];
#pragma unroll
    for (int j = 0; j < 2; ++j) {
      bv[j] = *(const bf16x8*)(VTl + (wid * 32 + j * 16 + lq) * 72 + ks * 32 + quad * 8);
      sf[j] = *(const bf16x8*)(KS + (wid * 32 + j * 16 + lq) * 72 + ks * 32 + quad * 8);
    }
#pragma unroll
    for (int i = 0; i < 4; ++i) {
      bf16x8 af = *(const bf16x8*)(AL + (i * 16 + lq) * 72 + ks * 32 + quad * 8);
      bf16x8 qf = *(const bf16x8*)(SQ + (i * 16 + lq) * 136 + ks * 32 + quad * 8);
#pragma unroll
      for (int j = 0; j < 2; ++j) {
        oa[i][j] = mfma16(af, bv[j], oa[i][j]);
        oa[i][j] = mfma16(qf, sf[j], oa[i][j]);
      }
    }
  }
  __syncthreads();

  // Phase 5: stage S^T half 2 (dk 64..127).
#pragma unroll
  for (int it = 0; it < 4; ++it) {
    const int p = tid + it * 256;
    const int dv = p >> 3, c8 = (p & 7) * 8;
    *(uint4*)(KS + dv * 72 + c8) =
        *(const uint4*)(S + sbase + (size_t)dv * 128 + 64 + c8);
  }
  __syncthreads();

  // Phase 6: o += q[:,64:128] * S[64:128,:].
#pragma unroll
  for (int ks = 0; ks < 2; ++ks) {
    bf16x8 sf[2];
#pragma unroll
    for (int j = 0; j < 2; ++j)
      sf[j] = *(const bf16x8*)(KS + (wid * 32 + j * 16 + lq) * 72 + ks * 32 + quad * 8);
#pragma unroll
    for (int i = 0; i < 4; ++i) {
      bf16x8 qf = *(const bf16x8*)(SQ + (i * 16 + lq) * 136 + (ks + 2) * 32 + quad * 8);
#pragma unroll
      for (int j = 0; j < 2; ++j) oa[i][j] = mfma16(qf, sf[j], oa[i][j]);
    }
  }
  __syncthreads();

  // Phase 7: spill o (fp32) to LDS for cross-wave RMSNorm.
#pragma unroll
  for (int i = 0; i < 4; ++i)
#pragma unroll
    for (int j = 0; j < 2; ++j)
#pragma unroll
      for (int r = 0; r < 4; ++r)
        OL[(i * 16 + quad * 4 + r) * 132 + wid * 32 + j * 16 + lq] = oa[i][j][r];
  __syncthreads();

  // Phase 8: row sum of squares, then scales.
  {
    const int r = tid >> 2, part = tid & 3;
    const float* pr = OL + r * 132 + part * 32;
    float s = 0.f;
#pragma unroll
    for (int c = 0; c < 32; ++c) { const float v = pr[c]; s += v * v; }
    RED[r * 4 + part] = s;
  }
  __syncthreads();
  if (tid < 64) {
    const float ms = (RED[tid * 4] + RED[tid * 4 + 1] + RED[tid * 4 + 2] + RED[tid * 4 + 3]) *
                     (1.f / 128.f);
    SCL[tid] = rsqrtf(ms + 1e-5f);
  }
  __syncthreads();

  // Phase 9: normalize * rms_w (f32), pack bf16, coalesced 16B stores.
#pragma unroll
  for (int it = 0; it < 4; ++it) {
    const int r = (tid >> 4) + it * 16;
    const int c8 = (tid & 15) * 8;
    const float sc = SCL[r];
    unsigned short us[8];
#pragma unroll
    for (int e = 0; e < 8; ++e)
      us[e] = f2bf(OL[r * 132 + c8 + e] * sc * rmsw[c8 + e]);
    uint4 pk;
    pk.x = (unsigned int)us[0] | ((unsigned int)us[1] << 16);
    pk.y = (unsigned int)us[2] | ((unsigned int)us[3] << 16);
    pk.z = (unsigned int)us[4] | ((unsigned int)us[5] << 16);
    pk.w = (unsigned int)us[6] | ((unsigned int)us[7] << 16);
    *(uint4*)(O + (size_t)(t0g + r) * 1024 + h * 128 + c8) = pk;
  }
}

// ---------------------------------------------------------------------------
extern "C" void kernel_launch(void* const* d_in, const int* in_sizes, int n_in,
                              void* d_out, int out_size, void* d_ws, size_t ws_size,
                              hipStream_t stream) {
  const float* X    = (const float*)d_in[0];
  const float* Wq   = (const float*)d_in[1];
  const float* Wk   = (const float*)d_in[2];
  const float* Wv   = (const float*)d_in[3];
  const float* fq1  = (const float*)d_in[4];
  const float* fqb1 = (const float*)d_in[5];
  const float* fq2  = (const float*)d_in[6];
  const float* fqb2 = (const float*)d_in[7];
  const float* fk1  = (const float*)d_in[8];
  const float* fkb1 = (const float*)d_in[9];
  const float* fk2  = (const float*)d_in[10];
  const float* fkb2 = (const float*)d_in[11];
  const float* rmsw = (const float*)d_in[12];
  const float* Wo   = (const float*)d_in[13];

  const size_t MB = 1u << 20;
  char* ws = (char*)d_ws;
  unsigned short* Q    = (unsigned short*)(ws);             // 32 MB (O in-place)
  unsigned short* Kf   = (unsigned short*)(ws + 32 * MB);   // 32 MB
  unsigned short* VT   = (unsigned short*)(ws + 64 * MB);   // 32 MB [b,h,dv,t]
  unsigned short* KV   = (unsigned short*)(ws + 96 * MB);   // 64 MB chunk states
  unsigned short* Xb   = KV;                                // 32 MB, dead after QKV
  unsigned short* Wqb  = (unsigned short*)(ws + 160 * MB);
  unsigned short* Wkb  = (unsigned short*)(ws + 162 * MB);
  unsigned short* Wvb  = (unsigned short*)(ws + 164 * MB);
  unsigned short* Wob  = (unsigned short*)(ws + 166 * MB);
  unsigned short* fq1b = (unsigned short*)(ws + 168 * MB);
  unsigned short* fq2b = fq1b + 16384;
  unsigned short* fk1b = fq1b + 32768;
  unsigned short* fk2b = fq1b + 49152;
  unsigned short* O    = Q;

  cvt4_kernel<<<dim3(1024, 4), 256, 0, stream>>>(Wq, Wk, Wv, Wo,
                                                 Wqb, Wkb, Wvb, Wob, 262144);
  cvt4_kernel<<<dim3(16, 4), 256, 0, stream>>>(fq1, fq2, fk1, fk2,
                                               fq1b, fq2b, fk1b, fk2b, 4096);
  cvt_kernel<<<16384, 256, 0, stream>>>(X, Xb, 4194304);  // X f32 -> bf16 once

  qkv_gemm<<<dim3(24, 128), 256, 0, stream>>>(Xb, Wqb, Wkb, Wvb, Q, Kf, VT);
  fm_kernel<<<dim3(256, 8, 2), 256, 0, stream>>>(Q, Kf, fq1b, fq2b, fk1b, fk2b,
                                                 fqb1, fqb2, fkb1, fkb2);
  kv_kernel<<<dim3(128, 16), 256, 0, stream>>>(Kf, VT, KV);
  cumsum_kernel<<<1024, 256, 0, stream>>>(KV);
  attn_kernel<<<dim3(128, 16), 256, 0, stream>>>(Q, Kf, VT, KV, rmsw, O);
  out_gemm<<<dim3(8, 128), 256, 0, stream>>>(O, Wob, (float*)d_out);
}

// Round 7
// 463.517 us; speedup vs baseline: 1.0165x; 1.0165x over previous
//
#include <hip/hip_runtime.h>

// ---------------------------------------------------------------------------
// LinearAttention forward. Inputs/outputs FLOAT32; internal compute bf16 MFMA
// with fp32 accumulation. B=2, T=8192 (BT=16384), HID=1024, H=8, DK=DV=128.
// ws layout (MB): [0,32) Q (O in-place) | [32,64) Kf | [64,96) VT |
//   [96,160) KV (Xb bf16 overlays [96,128) until QKV GEMM done) |
//   [160,168) Wq/Wk/Wv/Wo bf16 | [168,+128KB) fm weights bf16
// NOTE (R4): no fm fusion into qkv epilogue (+34.8KB LDS/+128 VGPR -> 291us).
// NOTE (R6): naive 32x32x16 fragment reads hit banks {0-7,16-23} only ->
//   3x SQ_LDS_BANK_CONFLICT, 158us. R7: XOR swizzle col ^= (row&3)*8 in LDS
//   (applied at staging via lane-permuted source cols) -> all 32 banks, 2-way.
// ---------------------------------------------------------------------------

typedef __bf16 bf16x8 __attribute__((ext_vector_type(8)));
typedef float  f32x4  __attribute__((ext_vector_type(4)));
typedef float  f32x16 __attribute__((ext_vector_type(16)));

__device__ __forceinline__ float bf2f(unsigned short u) {
  union { unsigned int i; float f; } v; v.i = ((unsigned int)u) << 16; return v.f;
}
__device__ __forceinline__ unsigned short f2bf(float f) {
  union { float f; unsigned int i; } v; v.f = f;
  return (unsigned short)((v.i + 0x8000u) >> 16);  // round-half-up
}
__device__ __forceinline__ unsigned int pk2(float a, float b) {
  union { float f; unsigned int i; } x, y; x.f = a; y.f = b;
  return ((x.i + 0x8000u) >> 16) | ((y.i + 0x8000u) & 0xFFFF0000u);
}
__device__ __forceinline__ f32x4 mfma16(bf16x8 a, bf16x8 b, f32x4 c) {
  return __builtin_amdgcn_mfma_f32_16x16x32_bf16(a, b, c, 0, 0, 0);
}
__device__ __forceinline__ f32x16 mfma32(bf16x8 a, bf16x8 b, f32x16 c) {
  return __builtin_amdgcn_mfma_f32_32x32x16_bf16(a, b, c, 0, 0, 0);
}
// Async global->LDS, 16B per lane. LDS dest = wave-uniform base + lane*16.
__device__ __forceinline__ void gl_lds16(const unsigned short* g, unsigned short* l) {
  __builtin_amdgcn_global_load_lds((const __attribute__((address_space(1))) void*)g,
                                   (__attribute__((address_space(3))) void*)l, 16, 0, 0);
}

// ---------------------------------------------------------------------------
// f32 -> bf16 converters. cvt4: four tensors in one launch (blockIdx.y picks).
// ---------------------------------------------------------------------------
__global__ void __launch_bounds__(256)
cvt_kernel(const float* __restrict__ s, unsigned short* __restrict__ d, int n4) {
  const int i = blockIdx.x * 256 + threadIdx.x;
  if (i >= n4) return;
  const float4 f = ((const float4*)s)[i];
  uint2 o; o.x = pk2(f.x, f.y); o.y = pk2(f.z, f.w);
  ((uint2*)d)[i] = o;
}
__global__ void __launch_bounds__(256)
cvt4_kernel(const float* __restrict__ s0, const float* __restrict__ s1,
            const float* __restrict__ s2, const float* __restrict__ s3,
            unsigned short* __restrict__ d0, unsigned short* __restrict__ d1,
            unsigned short* __restrict__ d2, unsigned short* __restrict__ d3,
            int n4) {
  const int w = blockIdx.y;
  const float* s = (w == 0) ? s0 : (w == 1) ? s1 : (w == 2) ? s2 : s3;
  unsigned short* d = (w == 0) ? d0 : (w == 1) ? d1 : (w == 2) ? d2 : d3;
  const int i = blockIdx.x * 256 + threadIdx.x;
  if (i >= n4) return;
  const float4 f = ((const float4*)s)[i];
  uint2 o; o.x = pk2(f.x, f.y); o.y = pk2(f.z, f.w);
  ((uint2*)d)[i] = o;
}

// ---------------------------------------------------------------------------
// Fused QKV GEMM (m97 staging, 32x32x16 MFMA, XOR-swizzled LDS).
// C[16384,3072] = Xb*[Wq;Wk;Wv]^T. Grid (24, 128): sel=bx>>3, (bx&7)*128 col.
// ---------------------------------------------------------------------------
__global__ void __launch_bounds__(256)
qkv_gemm(const unsigned short* __restrict__ Xb,
         const unsigned short* __restrict__ Wqb, const unsigned short* __restrict__ Wkb,
         const unsigned short* __restrict__ Wvb,
         unsigned short* __restrict__ Q, unsigned short* __restrict__ Kf,
         unsigned short* __restrict__ VT) {
  constexpr int K = 1024;
  __shared__ unsigned short As[128 * 32];
  __shared__ unsigned short Bs[128 * 32];
  const int tid = threadIdx.x;
  const int bx = blockIdx.x;
  const int rowBase = blockIdx.y * 128;
  const int sel = bx >> 3;
  const int colBase = (bx & 7) * 128;
  const unsigned short* Bw = (sel == 0) ? Wqb : ((sel == 1) ? Wkb : Wvb);

  const int lane = tid & 63, wid = tid >> 6;
  const int l31 = lane & 31, half = lane >> 5;
  const int wm = (wid >> 1) * 64, wn = (wid & 1) * 64;

  // Staging with XOR swizzle: lane fetches global col 8*((lane&3)^(row&3)),
  // so LDS[row][c] = global[row][c ^ (row&3)*8].
  const int srow = wid * 32 + (lane >> 2);
  const int scol = (((lane & 3) ^ ((lane >> 2) & 3)) * 8);
  const unsigned short* gA = Xb + (size_t)(rowBase + srow) * K + scol;
  const unsigned short* gB = Bw + (size_t)(colBase + srow) * K + scol;
  unsigned short* lA0 = As + wid * 1024;
  unsigned short* lA1 = As + wid * 1024 + 512;
  unsigned short* lB0 = Bs + wid * 1024;
  unsigned short* lB1 = Bs + wid * 1024 + 512;

  const int sw = (l31 & 3) * 8;  // read-side swizzle (row&3 == l31&3)

  f32x16 acc[2][2] = {};
  for (int kt = 0; kt < K / 32; ++kt) {
    __syncthreads();
    gl_lds16(gA + kt * 32, lA0);
    gl_lds16(gA + kt * 32 + 16 * K, lA1);
    gl_lds16(gB + kt * 32, lB0);
    gl_lds16(gB + kt * 32 + 16 * K, lB1);
    __syncthreads();
#pragma unroll
    for (int ks = 0; ks < 2; ++ks) {
      const int kos = (ks * 16 + half * 8) ^ sw;
      bf16x8 a0 = *(const bf16x8*)(As + (wm + l31) * 32 + kos);
      bf16x8 a1 = *(const bf16x8*)(As + (wm + 32 + l31) * 32 + kos);
      bf16x8 b0 = *(const bf16x8*)(Bs + (wn + l31) * 32 + kos);
      bf16x8 b1 = *(const bf16x8*)(Bs + (wn + 32 + l31) * 32 + kos);
      acc[0][0] = mfma32(a0, b0, acc[0][0]);
      acc[0][1] = mfma32(a0, b1, acc[0][1]);
      acc[1][0] = mfma32(a1, b0, acc[1][0]);
      acc[1][1] = mfma32(a1, b1, acc[1][1]);
    }
  }
  // C/D layout (32x32): col = lane&31, row = (r&3) + 8*(r>>2) + 4*half
  if (sel < 2) {
    unsigned short* C = (sel == 0) ? Q : Kf;
#pragma unroll
    for (int i = 0; i < 2; ++i)
#pragma unroll
      for (int j = 0; j < 2; ++j) {
        const int col = colBase + wn + j * 32 + l31;
#pragma unroll
        for (int a = 0; a < 4; ++a) {
          const int row0 = rowBase + wm + i * 32 + a * 8 + half * 4;
#pragma unroll
          for (int b4 = 0; b4 < 4; ++b4)
            C[(size_t)(row0 + b4) * 1024 + col] = f2bf(acc[i][j][a * 4 + b4]);
        }
      }
  } else {
#pragma unroll
    for (int i = 0; i < 2; ++i)
#pragma unroll
      for (int j = 0; j < 2; ++j) {
        const int col = colBase + wn + j * 32 + l31;   // 0..1023
        const int h = col >> 7, dv = col & 127;
#pragma unroll
        for (int a = 0; a < 4; ++a) {
          const int row0 = rowBase + wm + i * 32 + a * 8 + half * 4;  // 4 consec tokens
          const int b = row0 >> 13, tl = row0 & 8191;
          ushort4 t4;
          t4.x = f2bf(acc[i][j][a * 4 + 0]); t4.y = f2bf(acc[i][j][a * 4 + 1]);
          t4.z = f2bf(acc[i][j][a * 4 + 2]); t4.w = f2bf(acc[i][j][a * 4 + 3]);
          *(ushort4*)(VT + (((size_t)(b * 8 + h) * 128 + dv) << 13) + tl) = t4;
        }
      }
  }
}

// ---------------------------------------------------------------------------
// Final GEMM (m97 staging, 32x32x16 MFMA, XOR-swizzled LDS): out f32 = O*Wo^T.
// ---------------------------------------------------------------------------
__global__ void __launch_bounds__(256)
out_gemm(const unsigned short* __restrict__ A, const unsigned short* __restrict__ Bw,
         float* __restrict__ C) {
  constexpr int K = 1024;
  __shared__ unsigned short As[128 * 32];
  __shared__ unsigned short Bs[128 * 32];
  const int tid = threadIdx.x;
  const int rowBase = blockIdx.y * 128;
  const int colBase = blockIdx.x * 128;
  const int lane = tid & 63, wid = tid >> 6;
  const int l31 = lane & 31, half = lane >> 5;
  const int wm = (wid >> 1) * 64, wn = (wid & 1) * 64;

  const int srow = wid * 32 + (lane >> 2);
  const int scol = (((lane & 3) ^ ((lane >> 2) & 3)) * 8);
  const unsigned short* gA = A + (size_t)(rowBase + srow) * K + scol;
  const unsigned short* gB = Bw + (size_t)(colBase + srow) * K + scol;
  unsigned short* lA0 = As + wid * 1024;
  unsigned short* lA1 = As + wid * 1024 + 512;
  unsigned short* lB0 = Bs + wid * 1024;
  unsigned short* lB1 = Bs + wid * 1024 + 512;

  const int sw = (l31 & 3) * 8;

  f32x16 acc[2][2] = {};
  for (int kt = 0; kt < K / 32; ++kt) {
    __syncthreads();
    gl_lds16(gA + kt * 32, lA0);
    gl_lds16(gA + kt * 32 + 16 * K, lA1);
    gl_lds16(gB + kt * 32, lB0);
    gl_lds16(gB + kt * 32 + 16 * K, lB1);
    __syncthreads();
#pragma unroll
    for (int ks = 0; ks < 2; ++ks) {
      const int kos = (ks * 16 + half * 8) ^ sw;
      bf16x8 a0 = *(const bf16x8*)(As + (wm + l31) * 32 + kos);
      bf16x8 a1 = *(const bf16x8*)(As + (wm + 32 + l31) * 32 + kos);
      bf16x8 b0 = *(const bf16x8*)(Bs + (wn + l31) * 32 + kos);
      bf16x8 b1 = *(const bf16x8*)(Bs + (wn + 32 + l31) * 32 + kos);
      acc[0][0] = mfma32(a0, b0, acc[0][0]);
      acc[0][1] = mfma32(a0, b1, acc[0][1]);
      acc[1][0] = mfma32(a1, b0, acc[1][0]);
      acc[1][1] = mfma32(a1, b1, acc[1][1]);
    }
  }
#pragma unroll
  for (int i = 0; i < 2; ++i)
#pragma unroll
    for (int j = 0; j < 2; ++j) {
      const int col = colBase + wn + j * 32 + l31;
#pragma unroll
      for (int a = 0; a < 4; ++a) {
        const int row0 = rowBase + wm + i * 32 + a * 8 + half * 4;
#pragma unroll
        for (int b4 = 0; b4 < 4; ++b4)
          C[(size_t)(row0 + b4) * 1024 + col] = acc[i][j][a * 4 + b4];
      }
    }
}

// ---------------------------------------------------------------------------
// Feature map (per head): buf = (buf@w1^T + b1) * (buf@w2^T + b2) * scale,
// in place. Grid (BT/64, 8, 2): z=0 -> Q params, z=1 -> K params.
// ---------------------------------------------------------------------------
__global__ void __launch_bounds__(256)
fm_kernel(unsigned short* __restrict__ Qb, unsigned short* __restrict__ Kb,
          const unsigned short* __restrict__ fq1b, const unsigned short* __restrict__ fq2b,
          const unsigned short* __restrict__ fk1b, const unsigned short* __restrict__ fk2b,
          const float* __restrict__ fqb1, const float* __restrict__ fqb2,
          const float* __restrict__ fkb1, const float* __restrict__ fkb2) {
  __shared__ unsigned short Aq[64 * 136];
  const int z = blockIdx.z;
  unsigned short* buf = z ? Kb : Qb;
  const unsigned short* w1b = z ? fk1b : fq1b;
  const unsigned short* w2b = z ? fk2b : fq2b;
  const float* b1 = z ? fkb1 : fqb1;
  const float* b2 = z ? fkb2 : fqb2;
  const float scale = z ? 1.0f : 0.08838834764831843f;

  const int tid = threadIdx.x;
  const int t0 = blockIdx.x * 64;
  const int h = blockIdx.y, hc = h * 128;
#pragma unroll
  for (int it = 0; it < 4; ++it) {
    const int p = tid + it * 256;
    const int row = p >> 4, c8 = (p & 15) * 8;
    *(uint4*)(Aq + row * 136 + c8) =
        *(const uint4*)(buf + (size_t)(t0 + row) * 1024 + hc + c8);
  }
  __syncthreads();
  const int lane = tid & 63, wid = tid >> 6, lq = lane & 15, quad = lane >> 4;
  const int wn = wid * 32;
  f32x4 a1[4][2] = {}, a2[4][2] = {};
#pragma unroll
  for (int ks = 0; ks < 4; ++ks) {
    bf16x8 af[4];
#pragma unroll
    for (int i = 0; i < 4; ++i)
      af[i] = *(const bf16x8*)(Aq + (i * 16 + lq) * 136 + ks * 32 + quad * 8);
#pragma unroll
    for (int j = 0; j < 2; ++j) {
      const int nr = wn + j * 16 + lq;
      bf16x8 w1f = *(const bf16x8*)(w1b + nr * 128 + ks * 32 + quad * 8);
      bf16x8 w2f = *(const bf16x8*)(w2b + nr * 128 + ks * 32 + quad * 8);
#pragma unroll
      for (int i = 0; i < 4; ++i) {
        a1[i][j] = mfma16(af[i], w1f, a1[i][j]);
        a2[i][j] = mfma16(af[i], w2f, a2[i][j]);
      }
    }
  }
#pragma unroll
  for (int j = 0; j < 2; ++j) {
    const int col = wn + j * 16 + lq;
    const float bb1 = b1[col], bb2 = b2[col];
#pragma unroll
    for (int i = 0; i < 4; ++i)
#pragma unroll
      for (int r = 0; r < 4; ++r) {
        const float v = (a1[i][j][r] + bb1) * (a2[i][j][r] + bb2) * scale;
        buf[(size_t)(t0 + i * 16 + quad * 4 + r) * 1024 + hc + col] = f2bf(v);
      }
  }
}

// ---------------------------------------------------------------------------
// Per-chunk KV outer product: KV[bh,n][dv][dk] = sum_c V[c][dv] * K[c][dk].
// ---------------------------------------------------------------------------
__global__ void __launch_bounds__(256)
kv_kernel(const unsigned short* __restrict__ Kf, const unsigned short* __restrict__ VT,
          unsigned short* __restrict__ KV) {
  __shared__ unsigned short Kt[128 * 72];
  __shared__ unsigned short Vt[128 * 72];
  const int tid = threadIdx.x;
  const int n = blockIdx.x, bh = blockIdx.y;
  const int b = bh >> 3, h = bh & 7;
  const int t0g = b * 8192 + n * 64;
  const int tl0 = n * 64;
#pragma unroll
  for (int it = 0; it < 4; ++it) {
    const int p = tid + it * 256;
    const int d = p >> 3, c8 = (p & 7) * 8;
    *(uint4*)(Vt + d * 72 + c8) =
        *(const uint4*)(VT + (((size_t)bh * 128 + d) << 13) + tl0 + c8);
    const int tok = p >> 4, c8k = (p & 15) * 8;
    const unsigned short* src = Kf + (size_t)(t0g + tok) * 1024 + h * 128 + c8k;
    ushort4 k0 = *(const ushort4*)(src);
    ushort4 k1 = *(const ushort4*)(src + 4);
    Kt[(c8k + 0) * 72 + tok] = k0.x; Kt[(c8k + 1) * 72 + tok] = k0.y;
    Kt[(c8k + 2) * 72 + tok] = k0.z; Kt[(c8k + 3) * 72 + tok] = k0.w;
    Kt[(c8k + 4) * 72 + tok] = k1.x; Kt[(c8k + 5) * 72 + tok] = k1.y;
    Kt[(c8k + 6) * 72 + tok] = k1.z; Kt[(c8k + 7) * 72 + tok] = k1.w;
  }
  __syncthreads();
  const int lane = tid & 63, wid = tid >> 6, lq = lane & 15, quad = lane >> 4;
  const int wm = (wid >> 1) * 64, wn = (wid & 1) * 64;
  f32x4 acc[4][4] = {};
#pragma unroll
  for (int ks = 0; ks < 2; ++ks) {
    bf16x8 af[4], bfr[4];
#pragma unroll
    for (int i = 0; i < 4; ++i)
      af[i] = *(const bf16x8*)(Vt + (wm + i * 16 + lq) * 72 + ks * 32 + quad * 8);
#pragma unroll
    for (int j = 0; j < 4; ++j)
      bfr[j] = *(const bf16x8*)(Kt + (wn + j * 16 + lq) * 72 + ks * 32 + quad * 8);
#pragma unroll
    for (int i = 0; i < 4; ++i)
#pragma unroll
      for (int j = 0; j < 4; ++j) acc[i][j] = mfma16(af[i], bfr[j], acc[i][j]);
  }
  const size_t base = ((size_t)bh * 128 + n) * 16384;
#pragma unroll
  for (int i = 0; i < 4; ++i)
#pragma unroll
    for (int j = 0; j < 4; ++j)
#pragma unroll
      for (int r = 0; r < 4; ++r)
        KV[base + (size_t)(wm + i * 16 + quad * 4 + r) * 128 + wn + j * 16 + lq] =
            f2bf(acc[i][j][r]);
}

// ---------------------------------------------------------------------------
// Exclusive prefix sum of per-chunk KV states over n (128 chunks), in place.
// ---------------------------------------------------------------------------
__global__ void __launch_bounds__(256)
cumsum_kernel(unsigned short* __restrict__ KV) {
  const int idx = blockIdx.x * 256 + threadIdx.x;  // 0..262143
  const int bh = idx >> 14, e = idx & 16383;
  unsigned short* p = KV + (size_t)bh * (128 * 16384) + e;
  float run = 0.f;
  for (int n = 0; n < 128; ++n) {
    const float x = bf2f(*p);
    *p = f2bf(run);  // exclusive
    run += x;
    p += 16384;
  }
}

// ---------------------------------------------------------------------------
// Attention chunk kernel: o = tril(q k^T) v + q S, fused RMSNorm, per (b,h,n).
// O aliases Q (global Q reads only in phase 1; O written in phase 9).
// ---------------------------------------------------------------------------
__global__ void __launch_bounds__(256)
attn_kernel(const unsigned short* __restrict__ Q, const unsigned short* __restrict__ Kf,
            const unsigned short* __restrict__ VT, const unsigned short* __restrict__ S,
            const float* __restrict__ rmsw, unsigned short* __restrict__ O) {
  __shared__ uint4 smem4[3968];  // 63488 B
  unsigned short* sm = (unsigned short*)smem4;
  unsigned short* SQ = sm;            // stride 136
  unsigned short* KS = sm + 8704;
  unsigned short* VTl = sm + 17920;   // stride 72
  unsigned short* AL = sm + 27136;    // stride 72
  float* OL = (float*)sm;             // stride 132
  float* RED = (float*)AL;
  float* SCL = RED + 256;

  const int tid = threadIdx.x;
  const int n = blockIdx.x, bh = blockIdx.y;
  const int b = bh >> 3, h = bh & 7;
  const int t0g = b * 8192 + n * 64;
  const int tl0 = n * 64;
  const int lane = tid & 63, wid = tid >> 6, lq = lane & 15, quad = lane >> 4;

  // Phase 1: stage q, k (row-major) and V^T.
#pragma unroll
  for (int it = 0; it < 4; ++it) {
    const int p = tid + it * 256;
    const int row = p >> 4, c8 = (p & 15) * 8;
    *(uint4*)(SQ + row * 136 + c8) =
        *(const uint4*)(Q + (size_t)(t0g + row) * 1024 + h * 128 + c8);
    *(uint4*)(KS + row * 136 + c8) =
        *(const uint4*)(Kf + (size_t)(t0g + row) * 1024 + h * 128 + c8);
    const int d = p >> 3, c8b = (p & 7) * 8;
    *(uint4*)(VTl + d * 72 + c8b) =
        *(const uint4*)(VT + (((size_t)bh * 128 + d) << 13) + tl0 + c8b);
  }
  __syncthreads();

  // Phase 2: A = q k^T (wave w owns k-positions w*16..+15), mask, -> AL.
  {
    f32x4 aa[4] = {};
#pragma unroll
    for (int ks = 0; ks < 4; ++ks) {
      bf16x8 kf = *(const bf16x8*)(KS + (wid * 16 + lq) * 136 + ks * 32 + quad * 8);
#pragma unroll
      for (int i = 0; i < 4; ++i) {
        bf16x8 qf = *(const bf16x8*)(SQ + (i * 16 + lq) * 136 + ks * 32 + quad * 8);
        aa[i] = mfma16(qf, kf, aa[i]);
      }
    }
#pragma unroll
    for (int i = 0; i < 4; ++i)
#pragma unroll
      for (int r = 0; r < 4; ++r) {
        const int qp = i * 16 + quad * 4 + r, kp = wid * 16 + lq;
        AL[qp * 72 + kp] = f2bf(kp <= qp ? aa[i][r] : 0.f);
      }
  }
  __syncthreads();

  const size_t sbase = ((size_t)bh * 128 + n) * 16384;
  // Phase 3: stage S^T half 1 (dk 0..63) over KS.
#pragma unroll
  for (int it = 0; it < 4; ++it) {
    const int p = tid + it * 256;
    const int dv = p >> 3, c8 = (p & 7) * 8;
    *(uint4*)(KS + dv * 72 + c8) = *(const uint4*)(S + sbase + (size_t)dv * 128 + c8);
  }
  __syncthreads();

  f32x4 oa[4][2] = {};
  // Phase 4: o += A_masked * V  and  o += q[:,0:64] * S[0:64,:].
#pragma unroll
  for (int ks = 0; ks < 2; ++ks) {
    bf16x8 bv[2], sf[2];
#pragma unroll
    for (int j = 0; j < 2; ++j) {
      bv[j] = *(const bf16x8*)(VTl + (wid * 32 + j * 16 + lq) * 72 + ks * 32 + quad * 8);
      sf[j] = *(const bf16x8*)(KS + (wid * 32 + j * 16 + lq) * 72 + ks * 32 + quad * 8);
    }
#pragma unroll
    for (int i = 0; i < 4; ++i) {
      bf16x8 af = *(const bf16x8*)(AL + (i * 16 + lq) * 72 + ks * 32 + quad * 8);
      bf16x8 qf = *(const bf16x8*)(SQ + (i * 16 + lq) * 136 + ks * 32 + quad * 8);
#pragma unroll
      for (int j = 0; j < 2; ++j) {
        oa[i][j] = mfma16(af, bv[j], oa[i][j]);
        oa[i][j] = mfma16(qf, sf[j], oa[i][j]);
      }
    }
  }
  __syncthreads();

  // Phase 5: stage S^T half 2 (dk 64..127).
#pragma unroll
  for (int it = 0; it < 4; ++it) {
    const int p = tid + it * 256;
    const int dv = p >> 3, c8 = (p & 7) * 8;
    *(uint4*)(KS + dv * 72 + c8) =
        *(const uint4*)(S + sbase + (size_t)dv * 128 + 64 + c8);
  }
  __syncthreads();

  // Phase 6: o += q[:,64:128] * S[64:128,:].
#pragma unroll
  for (int ks = 0; ks < 2; ++ks) {
    bf16x8 sf[2];
#pragma unroll
    for (int j = 0; j < 2; ++j)
      sf[j] = *(const bf16x8*)(KS + (wid * 32 + j * 16 + lq) * 72 + ks * 32 + quad * 8);
#pragma unroll
    for (int i = 0; i < 4; ++i) {
      bf16x8 qf = *(const bf16x8*)(SQ + (i * 16 + lq) * 136 + (ks + 2) * 32 + quad * 8);
#pragma unroll
      for (int j = 0; j < 2; ++j) oa[i][j] = mfma16(qf, sf[j], oa[i][j]);
    }
  }
  __syncthreads();

  // Phase 7: spill o (fp32) to LDS for cross-wave RMSNorm.
#pragma unroll
  for (int i = 0; i < 4; ++i)
#pragma unroll
    for (int j = 0; j < 2; ++j)
#pragma unroll
      for (int r = 0; r < 4; ++r)
        OL[(i * 16 + quad * 4 + r) * 132 + wid * 32 + j * 16 + lq] = oa[i][j][r];
  __syncthreads();

  // Phase 8: row sum of squares, then scales.
  {
    const int r = tid >> 2, part = tid & 3;
    const float* pr = OL + r * 132 + part * 32;
    float s = 0.f;
#pragma unroll
    for (int c = 0; c < 32; ++c) { const float v = pr[c]; s += v * v; }
    RED[r * 4 + part] = s;
  }
  __syncthreads();
  if (tid < 64) {
    const float ms = (RED[tid * 4] + RED[tid * 4 + 1] + RED[tid * 4 + 2] + RED[tid * 4 + 3]) *
                     (1.f / 128.f);
    SCL[tid] = rsqrtf(ms + 1e-5f);
  }
  __syncthreads();

  // Phase 9: normalize * rms_w (f32), pack bf16, coalesced 16B stores.
#pragma unroll
  for (int it = 0; it < 4; ++it) {
    const int r = (tid >> 4) + it * 16;
    const int c8 = (tid & 15) * 8;
    const float sc = SCL[r];
    unsigned short us[8];
#pragma unroll
    for (int e = 0; e < 8; ++e)
      us[e] = f2bf(OL[r * 132 + c8 + e] * sc * rmsw[c8 + e]);
    uint4 pk;
    pk.x = (unsigned int)us[0] | ((unsigned int)us[1] << 16);
    pk.y = (unsigned int)us[2] | ((unsigned int)us[3] << 16);
    pk.z = (unsigned int)us[4] | ((unsigned int)us[5] << 16);
    pk.w = (unsigned int)us[6] | ((unsigned int)us[7] << 16);
    *(uint4*)(O + (size_t)(t0g + r) * 1024 + h * 128 + c8) = pk;
  }
}

// ---------------------------------------------------------------------------
extern "C" void kernel_launch(void* const* d_in, const int* in_sizes, int n_in,
                              void* d_out, int out_size, void* d_ws, size_t ws_size,
                              hipStream_t stream) {
  const float* X    = (const float*)d_in[0];
  const float* Wq   = (const float*)d_in[1];
  const float* Wk   = (const float*)d_in[2];
  const float* Wv   = (const float*)d_in[3];
  const float* fq1  = (const float*)d_in[4];
  const float* fqb1 = (const float*)d_in[5];
  const float* fq2  = (const float*)d_in[6];
  const float* fqb2 = (const float*)d_in[7];
  const float* fk1  = (const float*)d_in[8];
  const float* fkb1 = (const float*)d_in[9];
  const float* fk2  = (const float*)d_in[10];
  const float* fkb2 = (const float*)d_in[11];
  const float* rmsw = (const float*)d_in[12];
  const float* Wo   = (const float*)d_in[13];

  const size_t MB = 1u << 20;
  char* ws = (char*)d_ws;
  unsigned short* Q    = (unsigned short*)(ws);             // 32 MB (O in-place)
  unsigned short* Kf   = (unsigned short*)(ws + 32 * MB);   // 32 MB
  unsigned short* VT   = (unsigned short*)(ws + 64 * MB);   // 32 MB [b,h,dv,t]
  unsigned short* KV   = (unsigned short*)(ws + 96 * MB);   // 64 MB chunk states
  unsigned short* Xb   = KV;                                // 32 MB, dead after QKV
  unsigned short* Wqb  = (unsigned short*)(ws + 160 * MB);
  unsigned short* Wkb  = (unsigned short*)(ws + 162 * MB);
  unsigned short* Wvb  = (unsigned short*)(ws + 164 * MB);
  unsigned short* Wob  = (unsigned short*)(ws + 166 * MB);
  unsigned short* fq1b = (unsigned short*)(ws + 168 * MB);
  unsigned short* fq2b = fq1b + 16384;
  unsigned short* fk1b = fq1b + 32768;
  unsigned short* fk2b = fq1b + 49152;
  unsigned short* O    = Q;

  cvt4_kernel<<<dim3(1024, 4), 256, 0, stream>>>(Wq, Wk, Wv, Wo,
                                                 Wqb, Wkb, Wvb, Wob, 262144);
  cvt4_kernel<<<dim3(16, 4), 256, 0, stream>>>(fq1, fq2, fk1, fk2,
                                               fq1b, fq2b, fk1b, fk2b, 4096);
  cvt_kernel<<<16384, 256, 0, stream>>>(X, Xb, 4194304);  // X f32 -> bf16 once

  qkv_gemm<<<dim3(24, 128), 256, 0, stream>>>(Xb, Wqb, Wkb, Wvb, Q, Kf, VT);
  fm_kernel<<<dim3(256, 8, 2), 256, 0, stream>>>(Q, Kf, fq1b, fq2b, fk1b, fk2b,
                                                 fqb1, fqb2, fkb1, fkb2);
  kv_kernel<<<dim3(128, 16), 256, 0, stream>>>(Kf, VT, KV);
  cumsum_kernel<<<1024, 256, 0, stream>>>(KV);
  attn_kernel<<<dim3(128, 16), 256, 0, stream>>>(Q, Kf, VT, KV, rmsw, O);
  out_gemm<<<dim3(8, 128), 256, 0, stream>>>(O, Wob, (float*)d_out);
}

// Round 8
// 448.662 us; speedup vs baseline: 1.0501x; 1.0331x over previous
//
#include <hip/hip_runtime.h>

// ---------------------------------------------------------------------------
// LinearAttention forward. Inputs/outputs FLOAT32; internal compute bf16 MFMA
// with fp32 accumulation. B=2, T=8192 (BT=16384), HID=1024, H=8, DK=DV=128.
// ws layout (MB): [0,32) Q (O in-place) | [32,64) Kf | [64,96) VT |
//   [96,160) KV (Xb bf16 overlays [96,128) until QKV GEMM done) |
//   [160,168) Wq/Wk/Wv/Wo bf16 | [168,+128KB) fm weights bf16
// NOTE (R4): no fm fusion into qkv epilogue (+34.8KB LDS/+128 VGPR -> 291us).
// NOTE (R6/R7): 32x32x16 MFMA on this BK=32 staging layout has 3x LDS bank
//   conflicts (3.78e7 vs 1.26e7) that an XOR read swizzle did NOT fix
//   (counter bit-identical) -> 153-158us vs 141us. 16x16x32 fragment geometry
//   (row=lq, col=quad*16B) is bank-optimal here. Do not retry 32x32 without a
//   fundamentally different LDS layout.
// R8: fm processes 4 token-tiles/block with W-fragments register-hoisted.
// ---------------------------------------------------------------------------

typedef __bf16 bf16x8 __attribute__((ext_vector_type(8)));
typedef float  f32x4  __attribute__((ext_vector_type(4)));

__device__ __forceinline__ float bf2f(unsigned short u) {
  union { unsigned int i; float f; } v; v.i = ((unsigned int)u) << 16; return v.f;
}
__device__ __forceinline__ unsigned short f2bf(float f) {
  union { float f; unsigned int i; } v; v.f = f;
  return (unsigned short)((v.i + 0x8000u) >> 16);  // round-half-up
}
__device__ __forceinline__ unsigned int pk2(float a, float b) {
  union { float f; unsigned int i; } x, y; x.f = a; y.f = b;
  return ((x.i + 0x8000u) >> 16) | ((y.i + 0x8000u) & 0xFFFF0000u);
}
__device__ __forceinline__ f32x4 mfma16(bf16x8 a, bf16x8 b, f32x4 c) {
  return __builtin_amdgcn_mfma_f32_16x16x32_bf16(a, b, c, 0, 0, 0);
}
// Async global->LDS, 16B per lane. LDS dest = wave-uniform base + lane*16.
__device__ __forceinline__ void gl_lds16(const unsigned short* g, unsigned short* l) {
  __builtin_amdgcn_global_load_lds((const __attribute__((address_space(1))) void*)g,
                                   (__attribute__((address_space(3))) void*)l, 16, 0, 0);
}

// ---------------------------------------------------------------------------
// f32 -> bf16 converters. cvt4: four tensors in one launch (blockIdx.y picks).
// ---------------------------------------------------------------------------
__global__ void __launch_bounds__(256)
cvt_kernel(const float* __restrict__ s, unsigned short* __restrict__ d, int n4) {
  const int i = blockIdx.x * 256 + threadIdx.x;
  if (i >= n4) return;
  const float4 f = ((const float4*)s)[i];
  uint2 o; o.x = pk2(f.x, f.y); o.y = pk2(f.z, f.w);
  ((uint2*)d)[i] = o;
}
__global__ void __launch_bounds__(256)
cvt4_kernel(const float* __restrict__ s0, const float* __restrict__ s1,
            const float* __restrict__ s2, const float* __restrict__ s3,
            unsigned short* __restrict__ d0, unsigned short* __restrict__ d1,
            unsigned short* __restrict__ d2, unsigned short* __restrict__ d3,
            int n4) {
  const int w = blockIdx.y;
  const float* s = (w == 0) ? s0 : (w == 1) ? s1 : (w == 2) ? s2 : s3;
  unsigned short* d = (w == 0) ? d0 : (w == 1) ? d1 : (w == 2) ? d2 : d3;
  const int i = blockIdx.x * 256 + threadIdx.x;
  if (i >= n4) return;
  const float4 f = ((const float4*)s)[i];
  uint2 o; o.x = pk2(f.x, f.y); o.y = pk2(f.z, f.w);
  ((uint2*)d)[i] = o;
}

// ---------------------------------------------------------------------------
// Fused QKV GEMM (m97 structure, 16x16x32): C[16384,3072] = Xb*[Wq;Wk;Wv]^T.
// Grid (24, 128): sel = bx>>3 (0=Q,1=K,2=V), (bx&7)*128 = col base.
// 128x128 tile, BK=32, 256 threads, global_load_lds width-16 staging.
// ---------------------------------------------------------------------------
__global__ void __launch_bounds__(256)
qkv_gemm(const unsigned short* __restrict__ Xb,
         const unsigned short* __restrict__ Wqb, const unsigned short* __restrict__ Wkb,
         const unsigned short* __restrict__ Wvb,
         unsigned short* __restrict__ Q, unsigned short* __restrict__ Kf,
         unsigned short* __restrict__ VT) {
  constexpr int K = 1024;
  __shared__ unsigned short As[128 * 32];
  __shared__ unsigned short Bs[128 * 32];
  const int tid = threadIdx.x;
  const int bx = blockIdx.x;
  const int rowBase = blockIdx.y * 128;
  const int sel = bx >> 3;
  const int colBase = (bx & 7) * 128;
  const unsigned short* Bw = (sel == 0) ? Wqb : ((sel == 1) ? Wkb : Wvb);

  const int lane = tid & 63, wid = tid >> 6;
  const int lq = lane & 15, quad = lane >> 4;
  const int wm = (wid >> 1) * 64, wn = (wid & 1) * 64;

  const int srow = wid * 32 + (lane >> 2);
  const int scol = (lane & 3) * 8;
  const unsigned short* gA = Xb + (size_t)(rowBase + srow) * K + scol;
  const unsigned short* gB = Bw + (size_t)(colBase + srow) * K + scol;
  unsigned short* lA0 = As + wid * 1024;
  unsigned short* lA1 = As + wid * 1024 + 512;
  unsigned short* lB0 = Bs + wid * 1024;
  unsigned short* lB1 = Bs + wid * 1024 + 512;

  f32x4 acc[4][4] = {};
  for (int kt = 0; kt < K / 32; ++kt) {
    __syncthreads();
    gl_lds16(gA + kt * 32, lA0);
    gl_lds16(gA + kt * 32 + 16 * K, lA1);
    gl_lds16(gB + kt * 32, lB0);
    gl_lds16(gB + kt * 32 + 16 * K, lB1);
    __syncthreads();
    bf16x8 af[4], bfr[4];
#pragma unroll
    for (int i = 0; i < 4; ++i)
      af[i] = *(const bf16x8*)(As + (wm + i * 16 + lq) * 32 + quad * 8);
#pragma unroll
    for (int j = 0; j < 4; ++j)
      bfr[j] = *(const bf16x8*)(Bs + (wn + j * 16 + lq) * 32 + quad * 8);
#pragma unroll
    for (int i = 0; i < 4; ++i)
#pragma unroll
      for (int j = 0; j < 4; ++j) acc[i][j] = mfma16(af[i], bfr[j], acc[i][j]);
  }
  // C/D layout: col = lane&15, row = quad*4 + reg  [m89-verified]
  if (sel < 2) {
    unsigned short* C = (sel == 0) ? Q : Kf;
#pragma unroll
    for (int i = 0; i < 4; ++i)
#pragma unroll
      for (int j = 0; j < 4; ++j) {
        const int col = colBase + wn + j * 16 + lq;
#pragma unroll
        for (int r = 0; r < 4; ++r) {
          const int row = rowBase + wm + i * 16 + quad * 4 + r;
          C[(size_t)row * 1024 + col] = f2bf(acc[i][j][r]);
        }
      }
  } else {
#pragma unroll
    for (int i = 0; i < 4; ++i)
#pragma unroll
      for (int j = 0; j < 4; ++j) {
        const int col = colBase + wn + j * 16 + lq;   // 0..1023
        const int h = col >> 7, dv = col & 127;
        const int row0 = rowBase + wm + i * 16 + quad * 4;
        const int b = row0 >> 13, tl = row0 & 8191;
        ushort4 t4;
        t4.x = f2bf(acc[i][j][0]); t4.y = f2bf(acc[i][j][1]);
        t4.z = f2bf(acc[i][j][2]); t4.w = f2bf(acc[i][j][3]);
        *(ushort4*)(VT + (((size_t)(b * 8 + h) * 128 + dv) << 13) + tl) = t4;
      }
  }
}

// ---------------------------------------------------------------------------
// Final GEMM (m97 structure, 16x16x32): out[16384,1024] f32 = O * Wo^T.
// ---------------------------------------------------------------------------
__global__ void __launch_bounds__(256)
out_gemm(const unsigned short* __restrict__ A, const unsigned short* __restrict__ Bw,
         float* __restrict__ C) {
  constexpr int K = 1024;
  __shared__ unsigned short As[128 * 32];
  __shared__ unsigned short Bs[128 * 32];
  const int tid = threadIdx.x;
  const int rowBase = blockIdx.y * 128;
  const int colBase = blockIdx.x * 128;
  const int lane = tid & 63, wid = tid >> 6;
  const int lq = lane & 15, quad = lane >> 4;
  const int wm = (wid >> 1) * 64, wn = (wid & 1) * 64;

  const int srow = wid * 32 + (lane >> 2);
  const int scol = (lane & 3) * 8;
  const unsigned short* gA = A + (size_t)(rowBase + srow) * K + scol;
  const unsigned short* gB = Bw + (size_t)(colBase + srow) * K + scol;
  unsigned short* lA0 = As + wid * 1024;
  unsigned short* lA1 = As + wid * 1024 + 512;
  unsigned short* lB0 = Bs + wid * 1024;
  unsigned short* lB1 = Bs + wid * 1024 + 512;

  f32x4 acc[4][4] = {};
  for (int kt = 0; kt < K / 32; ++kt) {
    __syncthreads();
    gl_lds16(gA + kt * 32, lA0);
    gl_lds16(gA + kt * 32 + 16 * K, lA1);
    gl_lds16(gB + kt * 32, lB0);
    gl_lds16(gB + kt * 32 + 16 * K, lB1);
    __syncthreads();
    bf16x8 af[4], bfr[4];
#pragma unroll
    for (int i = 0; i < 4; ++i)
      af[i] = *(const bf16x8*)(As + (wm + i * 16 + lq) * 32 + quad * 8);
#pragma unroll
    for (int j = 0; j < 4; ++j)
      bfr[j] = *(const bf16x8*)(Bs + (wn + j * 16 + lq) * 32 + quad * 8);
#pragma unroll
    for (int i = 0; i < 4; ++i)
#pragma unroll
      for (int j = 0; j < 4; ++j) acc[i][j] = mfma16(af[i], bfr[j], acc[i][j]);
  }
#pragma unroll
  for (int i = 0; i < 4; ++i)
#pragma unroll
    for (int j = 0; j < 4; ++j) {
      const int col = colBase + wn + j * 16 + lq;
#pragma unroll
      for (int r = 0; r < 4; ++r) {
        const int row = rowBase + wm + i * 16 + quad * 4 + r;
        C[(size_t)row * 1024 + col] = acc[i][j][r];
      }
    }
}

// ---------------------------------------------------------------------------
// Feature map (per head): buf = (buf@w1^T + b1) * (buf@w2^T + b2) * scale,
// in place. Grid (BT/256, 8, 2): z=0 -> Q params, z=1 -> K params.
// R8: 4 token-tiles (256 tokens) per block; W fragments loaded ONCE into
// registers and reused across tiles (4x fewer W fetches, fewer blocks).
// ---------------------------------------------------------------------------
__global__ void __launch_bounds__(256)
fm_kernel(unsigned short* __restrict__ Qb, unsigned short* __restrict__ Kb,
          const unsigned short* __restrict__ fq1b, const unsigned short* __restrict__ fq2b,
          const unsigned short* __restrict__ fk1b, const unsigned short* __restrict__ fk2b,
          const float* __restrict__ fqb1, const float* __restrict__ fqb2,
          const float* __restrict__ fkb1, const float* __restrict__ fkb2) {
  __shared__ unsigned short Aq[64 * 136];
  const int z = blockIdx.z;
  unsigned short* buf = z ? Kb : Qb;
  const unsigned short* w1b = z ? fk1b : fq1b;
  const unsigned short* w2b = z ? fk2b : fq2b;
  const float* b1 = z ? fkb1 : fqb1;
  const float* b2 = z ? fkb2 : fqb2;
  const float scale = z ? 1.0f : 0.08838834764831843f;

  const int tid = threadIdx.x;
  const int t0 = blockIdx.x * 256;
  const int h = blockIdx.y, hc = h * 128;
  const int lane = tid & 63, wid = tid >> 6, lq = lane & 15, quad = lane >> 4;
  const int wn = wid * 32;

  // Hoist W fragments (per wave: rows wn..wn+31 of w1,w2) into registers.
  bf16x8 w1f[4][2], w2f[4][2];
#pragma unroll
  for (int ks = 0; ks < 4; ++ks)
#pragma unroll
    for (int j = 0; j < 2; ++j) {
      const int nr = wn + j * 16 + lq;
      w1f[ks][j] = *(const bf16x8*)(w1b + nr * 128 + ks * 32 + quad * 8);
      w2f[ks][j] = *(const bf16x8*)(w2b + nr * 128 + ks * 32 + quad * 8);
    }

  const float bb1[2] = { b1[wn + lq], b1[wn + 16 + lq] };
  const float bb2[2] = { b2[wn + lq], b2[wn + 16 + lq] };

  for (int tt = 0; tt < 4; ++tt) {
    const int tb = t0 + tt * 64;
#pragma unroll
    for (int it = 0; it < 4; ++it) {
      const int p = tid + it * 256;
      const int row = p >> 4, c8 = (p & 15) * 8;
      *(uint4*)(Aq + row * 136 + c8) =
          *(const uint4*)(buf + (size_t)(tb + row) * 1024 + hc + c8);
    }
    __syncthreads();
    f32x4 a1[4][2] = {}, a2[4][2] = {};
#pragma unroll
    for (int ks = 0; ks < 4; ++ks) {
      bf16x8 af[4];
#pragma unroll
      for (int i = 0; i < 4; ++i)
        af[i] = *(const bf16x8*)(Aq + (i * 16 + lq) * 136 + ks * 32 + quad * 8);
#pragma unroll
      for (int j = 0; j < 2; ++j)
#pragma unroll
        for (int i = 0; i < 4; ++i) {
          a1[i][j] = mfma16(af[i], w1f[ks][j], a1[i][j]);
          a2[i][j] = mfma16(af[i], w2f[ks][j], a2[i][j]);
        }
    }
    __syncthreads();  // all Aq reads done before next tile's staging
#pragma unroll
    for (int j = 0; j < 2; ++j) {
      const int col = wn + j * 16 + lq;
#pragma unroll
      for (int i = 0; i < 4; ++i)
#pragma unroll
        for (int r = 0; r < 4; ++r) {
          const float v = (a1[i][j][r] + bb1[j]) * (a2[i][j][r] + bb2[j]) * scale;
          buf[(size_t)(tb + i * 16 + quad * 4 + r) * 1024 + hc + col] = f2bf(v);
        }
    }
  }
}

// ---------------------------------------------------------------------------
// Per-chunk KV outer product: KV[bh,n][dv][dk] = sum_c V[c][dv] * K[c][dk].
// ---------------------------------------------------------------------------
__global__ void __launch_bounds__(256)
kv_kernel(const unsigned short* __restrict__ Kf, const unsigned short* __restrict__ VT,
          unsigned short* __restrict__ KV) {
  __shared__ unsigned short Kt[128 * 72];
  __shared__ unsigned short Vt[128 * 72];
  const int tid = threadIdx.x;
  const int n = blockIdx.x, bh = blockIdx.y;
  const int b = bh >> 3, h = bh & 7;
  const int t0g = b * 8192 + n * 64;
  const int tl0 = n * 64;
#pragma unroll
  for (int it = 0; it < 4; ++it) {
    const int p = tid + it * 256;
    const int d = p >> 3, c8 = (p & 7) * 8;
    *(uint4*)(Vt + d * 72 + c8) =
        *(const uint4*)(VT + (((size_t)bh * 128 + d) << 13) + tl0 + c8);
    const int tok = p >> 4, c8k = (p & 15) * 8;
    const unsigned short* src = Kf + (size_t)(t0g + tok) * 1024 + h * 128 + c8k;
    ushort4 k0 = *(const ushort4*)(src);
    ushort4 k1 = *(const ushort4*)(src + 4);
    Kt[(c8k + 0) * 72 + tok] = k0.x; Kt[(c8k + 1) * 72 + tok] = k0.y;
    Kt[(c8k + 2) * 72 + tok] = k0.z; Kt[(c8k + 3) * 72 + tok] = k0.w;
    Kt[(c8k + 4) * 72 + tok] = k1.x; Kt[(c8k + 5) * 72 + tok] = k1.y;
    Kt[(c8k + 6) * 72 + tok] = k1.z; Kt[(c8k + 7) * 72 + tok] = k1.w;
  }
  __syncthreads();
  const int lane = tid & 63, wid = tid >> 6, lq = lane & 15, quad = lane >> 4;
  const int wm = (wid >> 1) * 64, wn = (wid & 1) * 64;
  f32x4 acc[4][4] = {};
#pragma unroll
  for (int ks = 0; ks < 2; ++ks) {
    bf16x8 af[4], bfr[4];
#pragma unroll
    for (int i = 0; i < 4; ++i)
      af[i] = *(const bf16x8*)(Vt + (wm + i * 16 + lq) * 72 + ks * 32 + quad * 8);
#pragma unroll
    for (int j = 0; j < 4; ++j)
      bfr[j] = *(const bf16x8*)(Kt + (wn + j * 16 + lq) * 72 + ks * 32 + quad * 8);
#pragma unroll
    for (int i = 0; i < 4; ++i)
#pragma unroll
      for (int j = 0; j < 4; ++j) acc[i][j] = mfma16(af[i], bfr[j], acc[i][j]);
  }
  const size_t base = ((size_t)bh * 128 + n) * 16384;
#pragma unroll
  for (int i = 0; i < 4; ++i)
#pragma unroll
    for (int j = 0; j < 4; ++j)
#pragma unroll
      for (int r = 0; r < 4; ++r)
        KV[base + (size_t)(wm + i * 16 + quad * 4 + r) * 128 + wn + j * 16 + lq] =
            f2bf(acc[i][j][r]);
}

// ---------------------------------------------------------------------------
// Exclusive prefix sum of per-chunk KV states over n (128 chunks), in place.
// ---------------------------------------------------------------------------
__global__ void __launch_bounds__(256)
cumsum_kernel(unsigned short* __restrict__ KV) {
  const int idx = blockIdx.x * 256 + threadIdx.x;  // 0..262143
  const int bh = idx >> 14, e = idx & 16383;
  unsigned short* p = KV + (size_t)bh * (128 * 16384) + e;
  float run = 0.f;
  for (int n = 0; n < 128; ++n) {
    const float x = bf2f(*p);
    *p = f2bf(run);  // exclusive
    run += x;
    p += 16384;
  }
}

// ---------------------------------------------------------------------------
// Attention chunk kernel: o = tril(q k^T) v + q S, fused RMSNorm, per (b,h,n).
// O aliases Q (global Q reads only in phase 1; O written in phase 9).
// ---------------------------------------------------------------------------
__global__ void __launch_bounds__(256)
attn_kernel(const unsigned short* __restrict__ Q, const unsigned short* __restrict__ Kf,
            const unsigned short* __restrict__ VT, const unsigned short* __restrict__ S,
            const float* __restrict__ rmsw, unsigned short* __restrict__ O) {
  __shared__ uint4 smem4[3968];  // 63488 B
  unsigned short* sm = (unsigned short*)smem4;
  unsigned short* SQ = sm;            // stride 136
  unsigned short* KS = sm + 8704;
  unsigned short* VTl = sm + 17920;   // stride 72
  unsigned short* AL = sm + 27136;    // stride 72
  float* OL = (float*)sm;             // stride 132
  float* RED = (float*)AL;
  float* SCL = RED + 256;

  const int tid = threadIdx.x;
  const int n = blockIdx.x, bh = blockIdx.y;
  const int b = bh >> 3, h = bh & 7;
  const int t0g = b * 8192 + n * 64;
  const int tl0 = n * 64;
  const int lane = tid & 63, wid = tid >> 6, lq = lane & 15, quad = lane >> 4;

  // Phase 1: stage q, k (row-major) and V^T.
#pragma unroll
  for (int it = 0; it < 4; ++it) {
    const int p = tid + it * 256;
    const int row = p >> 4, c8 = (p & 15) * 8;
    *(uint4*)(SQ + row * 136 + c8) =
        *(const uint4*)(Q + (size_t)(t0g + row) * 1024 + h * 128 + c8);
    *(uint4*)(KS + row * 136 + c8) =
        *(const uint4*)(Kf + (size_t)(t0g + row) * 1024 + h * 128 + c8);
    const int d = p >> 3, c8b = (p & 7) * 8;
    *(uint4*)(VTl + d * 72 + c8b) =
        *(const uint4*)(VT + (((size_t)bh * 128 + d) << 13) + tl0 + c8b);
  }
  __syncthreads();

  // Phase 2: A = q k^T (wave w owns k-positions w*16..+15), mask, -> AL.
  {
    f32x4 aa[4] = {};
#pragma unroll
    for (int ks = 0; ks < 4; ++ks) {
      bf16x8 kf = *(const bf16x8*)(KS + (wid * 16 + lq) * 136 + ks * 32 + quad * 8);
#pragma unroll
      for (int i = 0; i < 4; ++i) {
        bf16x8 qf = *(const bf16x8*)(SQ + (i * 16 + lq) * 136 + ks * 32 + quad * 8);
        aa[i] = mfma16(qf, kf, aa[i]);
      }
    }
#pragma unroll
    for (int i = 0; i < 4; ++i)
#pragma unroll
      for (int r = 0; r < 4; ++r) {
        const int qp = i * 16 + quad * 4 + r, kp = wid * 16 + lq;
        AL[qp * 72 + kp] = f2bf(kp <= qp ? aa[i][r] : 0.f);
      }
  }
  __syncthreads();

  const size_t sbase = ((size_t)bh * 128 + n) * 16384;
  // Phase 3: stage S^T half 1 (dk 0..63) over KS.
#pragma unroll
  for (int it = 0; it < 4; ++it) {
    const int p = tid + it * 256;
    const int dv = p >> 3, c8 = (p & 7) * 8;
    *(uint4*)(KS + dv * 72 + c8) = *(const uint4*)(S + sbase + (size_t)dv * 128 + c8);
  }
  __syncthreads();

  f32x4 oa[4][2] = {};
  // Phase 4: o += A_masked * V  and  o += q[:,0:64] * S[0:64,:].
#pragma unroll
  for (int ks = 0; ks < 2; ++ks) {
    bf16x8 bv[2], sf[2];
#pragma unroll
    for (int j = 0; j < 2; ++j) {
      bv[j] = *(const bf16x8*)(VTl + (wid * 32 + j * 16 + lq) * 72 + ks * 32 + quad * 8);
      sf[j] = *(const bf16x8*)(KS + (wid * 32 + j * 16 + lq) * 72 + ks * 32 + quad * 8);
    }
#pragma unroll
    for (int i = 0; i < 4; ++i) {
      bf16x8 af = *(const bf16x8*)(AL + (i * 16 + lq) * 72 + ks * 32 + quad * 8);
      bf16x8 qf = *(const bf16x8*)(SQ + (i * 16 + lq) * 136 + ks * 32 + quad * 8);
#pragma unroll
      for (int j = 0; j < 2; ++j) {
        oa[i][j] = mfma16(af, bv[j], oa[i][j]);
        oa[i][j] = mfma16(qf, sf[j], oa[i][j]);
      }
    }
  }
  __syncthreads();

  // Phase 5: stage S^T half 2 (dk 64..127).
#pragma unroll
  for (int it = 0; it < 4; ++it) {
    const int p = tid + it * 256;
    const int dv = p >> 3, c8 = (p & 7) * 8;
    *(uint4*)(KS + dv * 72 + c8) =
        *(const uint4*)(S + sbase + (size_t)dv * 128 + 64 + c8);
  }
  __syncthreads();

  // Phase 6: o += q[:,64:128] * S[64:128,:].
#pragma unroll
  for (int ks = 0; ks < 2; ++ks) {
    bf16x8 sf[2];
#pragma unroll
    for (int j = 0; j < 2; ++j)
      sf[j] = *(const bf16x8*)(KS + (wid * 32 + j * 16 + lq) * 72 + ks * 32 + quad * 8);
#pragma unroll
    for (int i = 0; i < 4; ++i) {
      bf16x8 qf = *(const bf16x8*)(SQ + (i * 16 + lq) * 136 + (ks + 2) * 32 + quad * 8);
#pragma unroll
      for (int j = 0; j < 2; ++j) oa[i][j] = mfma16(qf, sf[j], oa[i][j]);
    }
  }
  __syncthreads();

  // Phase 7: spill o (fp32) to LDS for cross-wave RMSNorm.
#pragma unroll
  for (int i = 0; i < 4; ++i)
#pragma unroll
    for (int j = 0; j < 2; ++j)
#pragma unroll
      for (int r = 0; r < 4; ++r)
        OL[(i * 16 + quad * 4 + r) * 132 + wid * 32 + j * 16 + lq] = oa[i][j][r];
  __syncthreads();

  // Phase 8: row sum of squares, then scales.
  {
    const int r = tid >> 2, part = tid & 3;
    const float* pr = OL + r * 132 + part * 32;
    float s = 0.f;
#pragma unroll
    for (int c = 0; c < 32; ++c) { const float v = pr[c]; s += v * v; }
    RED[r * 4 + part] = s;
  }
  __syncthreads();
  if (tid < 64) {
    const float ms = (RED[tid * 4] + RED[tid * 4 + 1] + RED[tid * 4 + 2] + RED[tid * 4 + 3]) *
                     (1.f / 128.f);
    SCL[tid] = rsqrtf(ms + 1e-5f);
  }
  __syncthreads();

  // Phase 9: normalize * rms_w (f32), pack bf16, coalesced 16B stores.
#pragma unroll
  for (int it = 0; it < 4; ++it) {
    const int r = (tid >> 4) + it * 16;
    const int c8 = (tid & 15) * 8;
    const float sc = SCL[r];
    unsigned short us[8];
#pragma unroll
    for (int e = 0; e < 8; ++e)
      us[e] = f2bf(OL[r * 132 + c8 + e] * sc * rmsw[c8 + e]);
    uint4 pk;
    pk.x = (unsigned int)us[0] | ((unsigned int)us[1] << 16);
    pk.y = (unsigned int)us[2] | ((unsigned int)us[3] << 16);
    pk.z = (unsigned int)us[4] | ((unsigned int)us[5] << 16);
    pk.w = (unsigned int)us[6] | ((unsigned int)us[7] << 16);
    *(uint4*)(O + (size_t)(t0g + r) * 1024 + h * 128 + c8) = pk;
  }
}

// ---------------------------------------------------------------------------
extern "C" void kernel_launch(void* const* d_in, const int* in_sizes, int n_in,
                              void* d_out, int out_size, void* d_ws, size_t ws_size,
                              hipStream_t stream) {
  const float* X    = (const float*)d_in[0];
  const float* Wq   = (const float*)d_in[1];
  const float* Wk   = (const float*)d_in[2];
  const float* Wv   = (const float*)d_in[3];
  const float* fq1  = (const float*)d_in[4];
  const float* fqb1 = (const float*)d_in[5];
  const float* fq2  = (const float*)d_in[6];
  const float* fqb2 = (const float*)d_in[7];
  const float* fk1  = (const float*)d_in[8];
  const float* fkb1 = (const float*)d_in[9];
  const float* fk2  = (const float*)d_in[10];
  const float* fkb2 = (const float*)d_in[11];
  const float* rmsw = (const float*)d_in[12];
  const float* Wo   = (const float*)d_in[13];

  const size_t MB = 1u << 20;
  char* ws = (char*)d_ws;
  unsigned short* Q    = (unsigned short*)(ws);             // 32 MB (O in-place)
  unsigned short* Kf   = (unsigned short*)(ws + 32 * MB);   // 32 MB
  unsigned short* VT   = (unsigned short*)(ws + 64 * MB);   // 32 MB [b,h,dv,t]
  unsigned short* KV   = (unsigned short*)(ws + 96 * MB);   // 64 MB chunk states
  unsigned short* Xb   = KV;                                // 32 MB, dead after QKV
  unsigned short* Wqb  = (unsigned short*)(ws + 160 * MB);
  unsigned short* Wkb  = (unsigned short*)(ws + 162 * MB);
  unsigned short* Wvb  = (unsigned short*)(ws + 164 * MB);
  unsigned short* Wob  = (unsigned short*)(ws + 166 * MB);
  unsigned short* fq1b = (unsigned short*)(ws + 168 * MB);
  unsigned short* fq2b = fq1b + 16384;
  unsigned short* fk1b = fq1b + 32768;
  unsigned short* fk2b = fq1b + 49152;
  unsigned short* O    = Q;

  cvt4_kernel<<<dim3(1024, 4), 256, 0, stream>>>(Wq, Wk, Wv, Wo,
                                                 Wqb, Wkb, Wvb, Wob, 262144);
  cvt4_kernel<<<dim3(16, 4), 256, 0, stream>>>(fq1, fq2, fk1, fk2,
                                               fq1b, fq2b, fk1b, fk2b, 4096);
  cvt_kernel<<<16384, 256, 0, stream>>>(X, Xb, 4194304);  // X f32 -> bf16 once

  qkv_gemm<<<dim3(24, 128), 256, 0, stream>>>(Xb, Wqb, Wkb, Wvb, Q, Kf, VT);
  fm_kernel<<<dim3(64, 8, 2), 256, 0, stream>>>(Q, Kf, fq1b, fq2b, fk1b, fk2b,
                                                fqb1, fqb2, fkb1, fkb2);
  kv_kernel<<<dim3(128, 16), 256, 0, stream>>>(Kf, VT, KV);
  cumsum_kernel<<<1024, 256, 0, stream>>>(KV);
  attn_kernel<<<dim3(128, 16), 256, 0, stream>>>(Q, Kf, VT, KV, rmsw, O);
  out_gemm<<<dim3(8, 128), 256, 0, stream>>>(O, Wob, (float*)d_out);
}